// Round 7
// baseline (98.329 us; speedup 1.0000x reference)
//
#include <hip/hip_runtime.h>

#define BT    192
#define NNODE 512
#define DIM   128
#define NH    4
#define DH    32
#define NE    4096
#define NROWS (BT * NNODE)

typedef __attribute__((ext_vector_type(8))) short  short8b;   // 8 bf16 (4 VGPR)
typedef __attribute__((ext_vector_type(4))) float  floatx4;   // MFMA acc
typedef __attribute__((ext_vector_type(8))) unsigned short ushort8;

__device__ inline unsigned short f2bf(float f) {              // RNE f32->bf16
    unsigned int u = __float_as_uint(f);
    return (unsigned short)((u + 0x7FFFu + ((u >> 16) & 1u)) >> 16);
}
__device__ inline float bflo(unsigned int v) { return __uint_as_float(v << 16); }
__device__ inline float bfhi(unsigned int v) { return __uint_as_float(v & 0xFFFF0000u); }

__device__ inline short8b pack8(float4 a, float4 b) {
    short8b r;
    r[0] = (short)f2bf(a.x); r[1] = (short)f2bf(a.y);
    r[2] = (short)f2bf(a.z); r[3] = (short)f2bf(a.w);
    r[4] = (short)f2bf(b.x); r[5] = (short)f2bf(b.y);
    r[6] = (short)f2bf(b.z); r[7] = (short)f2bf(b.w);
    return r;
}

// ---------------------------------------------------------------------------
// K0: merged CSR build + W pre-swizzle (unchanged from r5).
// ---------------------------------------------------------------------------
__global__ __launch_bounds__(512) void csr_build_k(
    const int* __restrict__ ei, const float* __restrict__ ew,
    const float* __restrict__ W,
    int* __restrict__ row_ptr, int* __restrict__ csr_src,
    float* __restrict__ csr_ew, unsigned short* __restrict__ wswz)
{
    __shared__ int dsts[NE];
    __shared__ int cnt[NNODE];
    __shared__ int scan[NNODE];
    int t = threadIdx.x;
    int b = blockIdx.x;

    if (b >= 64) {                        // ---- W pre-swizzle
        int j = (b - 64) * 512 + t;       // float4 index, 4096 total
        const float4* W4 = (const float4*)W;
        float4 wv = W4[j];
        int k = j >> 5, c4 = (j & 31) * 4;
        float vv[4] = { wv.x, wv.y, wv.z, wv.w };
#pragma unroll
        for (int e = 0; e < 4; ++e) {
            int col = c4 + e;
            int byte = col * 256 + ((2 * k) ^ ((col & 7) << 4));
            wswz[byte >> 1] = f2bf(vv[e]);
        }
        return;
    }

    for (int e = t; e < NE; e += 512) dsts[e] = ei[NE + e];
    cnt[t] = 0;
    __syncthreads();
    for (int e = t; e < NE; e += 512) atomicAdd(&cnt[dsts[e]], 1);
    __syncthreads();
    scan[t] = cnt[t];
    __syncthreads();
    for (int o = 1; o < NNODE; o <<= 1) {
        int v = (t >= o) ? scan[t - o] : 0;
        __syncthreads();
        scan[t] += v;
        __syncthreads();
    }
    if (b == 0) {
        if (t == 0) row_ptr[0] = 0;
        row_ptr[t + 1] = scan[t];
    }
    __syncthreads();

    int wave = t >> 6, lane = t & 63;
    int node = b * 8 + wave;
    int pos = scan[node] - cnt[node];     // exclusive prefix
    for (int c = 0; c < NE; c += 64) {
        int e = c + lane;
        int d = dsts[e];
        unsigned long long mask = __ballot(d == node);
        if (d == node) {
            int ofs = __popcll(mask & ((1ull << lane) - 1ull));
            csr_src[pos + ofs] = ei[e];
            csr_ew[pos + ofs]  = ew[e];
        }
        pos += __popcll(mask);
    }
}

// ---------------------------------------------------------------------------
// K1: bf16 MFMA projection GEMM  h = x @ W  + fused attention-score epilogue.
// 128 rows/block, 4 waves. While each 64-row half sits in the Ct LDS buffer
// (f32) for coalesced h stores, 4 threads/row also compute the per-head
// att_src/att_dst dots and write ssg/sdg (node-major, head-minor).
// att staged transposed (att_f[j*4+q]) -> conflict-free LDS reads.
// ---------------------------------------------------------------------------
__global__ __launch_bounds__(256) void gemm_mfma_k(
    const float* __restrict__ x, const unsigned short* __restrict__ wswz,
    const float* __restrict__ att_src, const float* __restrict__ att_dst,
    unsigned short* __restrict__ h, float* __restrict__ ssg,
    float* __restrict__ sdg)
{
    __shared__ __align__(16) char sm[64 * 132 * 4];   // 33792 B (W uses 32768)
    __shared__ float att_f[256];
    int t = threadIdx.x;
    if (t < 128) att_f[t] = att_src[(t & 3) * 32 + (t >> 2)];
    else         att_f[t] = att_dst[(t & 3) * 32 + ((t - 128) >> 2)];
    {
        const uint4* g = (const uint4*)wswz;          // 2048 x 16B
        uint4* ld = (uint4*)sm;
#pragma unroll
        for (int i = 0; i < 8; ++i) ld[t + i * 256] = g[t + i * 256];
    }
    int w = t >> 6, l = t & 63, lr = l & 15, lk = l >> 4;
    size_t base = (size_t)blockIdx.x * 128;
    const float* xA = x + (base + (size_t)w * 16 + lr) * DIM;
    const float* xB = xA + 64 * DIM;

    floatx4 accA[8], accB[8];
#pragma unroll
    for (int n = 0; n < 8; ++n) {
        accA[n] = (floatx4){0.f, 0.f, 0.f, 0.f};
        accB[n] = (floatx4){0.f, 0.f, 0.f, 0.f};
    }
    __syncthreads();

#pragma unroll
    for (int kk = 0; kk < 4; ++kk) {
        int k0 = kk * 32 + lk * 8;
        float4 a0 = *(const float4*)(xA + k0);
        float4 a1 = *(const float4*)(xA + k0 + 4);
        float4 b0 = *(const float4*)(xB + k0);
        float4 b1 = *(const float4*)(xB + k0 + 4);
        short8b av = pack8(a0, a1);
        short8b bv = pack8(b0, b1);
        int c = kk * 4 + lk;
#pragma unroll
        for (int n = 0; n < 8; ++n) {
            int col = n * 16 + lr;
            short8b bf = *(const short8b*)(sm + col * 256 + ((c ^ (col & 7)) << 4));
            accA[n] = __builtin_amdgcn_mfma_f32_16x16x32_bf16(av, bf, accA[n], 0, 0, 0);
            accB[n] = __builtin_amdgcn_mfma_f32_16x16x32_bf16(bv, bf, accB[n], 0, 0, 0);
        }
    }

    float* Ct = (float*)sm;
    unsigned short* hbase = h + base * DIM;
    int sr = t >> 2, sq = t & 3;                       // score row / head

    // ---- pass A: rows 0..63
    __syncthreads();
#pragma unroll
    for (int n = 0; n < 8; ++n)
#pragma unroll
        for (int j = 0; j < 4; ++j)
            Ct[(w * 16 + lk * 4 + j) * 132 + n * 16 + lr] = accA[n][j];
    __syncthreads();
#pragma unroll
    for (int i = 0; i < 4; ++i) {
        int chunk = t + i * 256;
        int row = chunk >> 4, cc = chunk & 15;
        const float* cp = Ct + row * 132 + cc * 8;
        ushort8 v;
#pragma unroll
        for (int e = 0; e < 8; ++e) v[e] = f2bf(cp[e]);
        *(ushort8*)(hbase + row * DIM + cc * 8) = v;
    }
    {
        const float* cp = Ct + sr * 132 + sq * 32;
        float ps = 0.f, pd = 0.f;
#pragma unroll
        for (int j = 0; j < 32; j += 4) {
            float4 cv = *(const float4*)(cp + j);
            ps = fmaf(cv.x, att_f[(j+0)*4 + sq], ps);
            ps = fmaf(cv.y, att_f[(j+1)*4 + sq], ps);
            ps = fmaf(cv.z, att_f[(j+2)*4 + sq], ps);
            ps = fmaf(cv.w, att_f[(j+3)*4 + sq], ps);
            pd = fmaf(cv.x, att_f[128 + (j+0)*4 + sq], pd);
            pd = fmaf(cv.y, att_f[128 + (j+1)*4 + sq], pd);
            pd = fmaf(cv.z, att_f[128 + (j+2)*4 + sq], pd);
            pd = fmaf(cv.w, att_f[128 + (j+3)*4 + sq], pd);
        }
        size_t grow = base + sr;
        ssg[grow * 4 + sq] = ps;
        sdg[grow * 4 + sq] = pd;
    }

    // ---- pass B: rows 64..127
    __syncthreads();
#pragma unroll
    for (int n = 0; n < 8; ++n)
#pragma unroll
        for (int j = 0; j < 4; ++j)
            Ct[(w * 16 + lk * 4 + j) * 132 + n * 16 + lr] = accB[n][j];
    __syncthreads();
#pragma unroll
    for (int i = 0; i < 4; ++i) {
        int chunk = t + i * 256;
        int row = chunk >> 4, cc = chunk & 15;
        const float* cp = Ct + row * 132 + cc * 8;
        ushort8 v;
#pragma unroll
        for (int e = 0; e < 8; ++e) v[e] = f2bf(cp[e]);
        *(ushort8*)(hbase + (64 + row) * DIM + cc * 8) = v;
    }
    {
        const float* cp = Ct + sr * 132 + sq * 32;
        float ps = 0.f, pd = 0.f;
#pragma unroll
        for (int j = 0; j < 32; j += 4) {
            float4 cv = *(const float4*)(cp + j);
            ps = fmaf(cv.x, att_f[(j+0)*4 + sq], ps);
            ps = fmaf(cv.y, att_f[(j+1)*4 + sq], ps);
            ps = fmaf(cv.z, att_f[(j+2)*4 + sq], ps);
            ps = fmaf(cv.w, att_f[(j+3)*4 + sq], ps);
            pd = fmaf(cv.x, att_f[128 + (j+0)*4 + sq], pd);
            pd = fmaf(cv.y, att_f[128 + (j+1)*4 + sq], pd);
            pd = fmaf(cv.z, att_f[128 + (j+2)*4 + sq], pd);
            pd = fmaf(cv.w, att_f[128 + (j+3)*4 + sq], pd);
        }
        size_t grow = base + 64 + sr;
        ssg[grow * 4 + sq] = ps;
        sdg[grow * 4 + sq] = pd;
    }
}

// ---------------------------------------------------------------------------
// K2: fused gather-aggregation + softmax-normalize + bias + LayerNorm + ELU.
// One thread per (bt, node) output row. h rows and scores read straight from
// global (per-bt slice is 128 KB -> L2-resident; no LDS staging). acc[128]
// lives in registers; LN is thread-local. No max pass (scores O(10), f32 exp
// safe; softmax ratio invariant).
// ---------------------------------------------------------------------------
__global__ __launch_bounds__(256) void agg_ln_k(
    const unsigned short* __restrict__ h,
    const float* __restrict__ ssg, const float* __restrict__ sdg,
    const int* __restrict__ row_ptr, const int* __restrict__ csr_src,
    const float* __restrict__ csr_ew,
    const float* __restrict__ bias, const float* __restrict__ gamma,
    const float* __restrict__ beta, float* __restrict__ out)
{
    __shared__ float bgb[384];
    int t = threadIdx.x;
    for (int i = t; i < 384; i += 256)
        bgb[i] = (i < 128) ? bias[i] : (i < 256) ? gamma[i - 128] : beta[i - 256];
    __syncthreads();

    int gid  = blockIdx.x * 256 + t;
    int node = gid & (NNODE - 1);
    int bt   = gid >> 9;
    const unsigned short* hb  = h   + (size_t)bt * NNODE * DIM;
    const float*          ssb = ssg + (size_t)bt * NNODE * 4;
    float4 sd = *(const float4*)(sdg + (size_t)gid * 4);
    int beg = row_ptr[node], end = row_ptr[node + 1];

    float acc[DIM];
#pragma unroll
    for (int d = 0; d < DIM; ++d) acc[d] = 0.f;
    float den0 = 0.f, den1 = 0.f, den2 = 0.f, den3 = 0.f;

    for (int e = beg; e < end; ++e) {
        int s   = csr_src[e];
        float w = csr_ew[e];
        float4 ss = *(const float4*)(ssb + s * 4);
        float e0 = ss.x + sd.x; e0 = (e0 > 0.f) ? e0 : 0.2f * e0;
        float e1 = ss.y + sd.y; e1 = (e1 > 0.f) ? e1 : 0.2f * e1;
        float e2 = ss.z + sd.z; e2 = (e2 > 0.f) ? e2 : 0.2f * e2;
        float e3 = ss.w + sd.w; e3 = (e3 > 0.f) ? e3 : 0.2f * e3;
        float p0 = __expf(e0 * w), p1 = __expf(e1 * w);
        float p2 = __expf(e2 * w), p3 = __expf(e3 * w);
        den0 += p0; den1 += p1; den2 += p2; den3 += p3;
        const uint4* hp = (const uint4*)(hb + (size_t)s * DIM);
#pragma unroll
        for (int q = 0; q < 4; ++q) {
            float pq = (q == 0) ? p0 : (q == 1) ? p1 : (q == 2) ? p2 : p3;
#pragma unroll
            for (int i = 0; i < 4; ++i) {
                uint4 v = hp[q * 4 + i];
                int d0 = q * 32 + i * 8;
                acc[d0+0] = fmaf(pq, bflo(v.x), acc[d0+0]);
                acc[d0+1] = fmaf(pq, bfhi(v.x), acc[d0+1]);
                acc[d0+2] = fmaf(pq, bflo(v.y), acc[d0+2]);
                acc[d0+3] = fmaf(pq, bfhi(v.y), acc[d0+3]);
                acc[d0+4] = fmaf(pq, bflo(v.z), acc[d0+4]);
                acc[d0+5] = fmaf(pq, bfhi(v.z), acc[d0+5]);
                acc[d0+6] = fmaf(pq, bflo(v.w), acc[d0+6]);
                acc[d0+7] = fmaf(pq, bfhi(v.w), acc[d0+7]);
            }
        }
    }

    // normalize per head + bias
#pragma unroll
    for (int q = 0; q < 4; ++q) {
        float dq  = (q == 0) ? den0 : (q == 1) ? den1 : (q == 2) ? den2 : den3;
        float inv = 1.f / (dq + 1e-16f);
#pragma unroll
        for (int j = 0; j < 32; ++j) {
            int d = q * 32 + j;
            acc[d] = fmaf(acc[d], inv, bgb[d]);
        }
    }

    // thread-local LayerNorm + ELU
    float s1 = 0.f, s2 = 0.f;
#pragma unroll
    for (int d = 0; d < DIM; ++d) { s1 += acc[d]; s2 = fmaf(acc[d], acc[d], s2); }
    float mean = s1 * (1.f / 128.f);
    float var  = s2 * (1.f / 128.f) - mean * mean;
    float rstd = rsqrtf(var + 1e-5f);

    float* op = out + (size_t)gid * DIM;
#pragma unroll
    for (int d = 0; d < DIM; d += 4) {
        float4 o4;
        float y0 = (acc[d+0] - mean) * rstd * bgb[128 + d+0] + bgb[256 + d+0];
        float y1 = (acc[d+1] - mean) * rstd * bgb[128 + d+1] + bgb[256 + d+1];
        float y2 = (acc[d+2] - mean) * rstd * bgb[128 + d+2] + bgb[256 + d+2];
        float y3 = (acc[d+3] - mean) * rstd * bgb[128 + d+3] + bgb[256 + d+3];
        o4.x = (y0 > 0.f) ? y0 : expm1f(y0);
        o4.y = (y1 > 0.f) ? y1 : expm1f(y1);
        o4.z = (y2 > 0.f) ? y2 : expm1f(y2);
        o4.w = (y3 > 0.f) ? y3 : expm1f(y3);
        *(float4*)(op + d) = o4;
    }
}

// ---------------------------------------------------------------------------
extern "C" void kernel_launch(void* const* d_in, const int* in_sizes, int n_in,
                              void* d_out, int out_size, void* d_ws, size_t ws_size,
                              hipStream_t stream)
{
    const float* x     = (const float*)d_in[0];
    const int*   ei    = (const int*)  d_in[1];
    const float* ew    = (const float*)d_in[2];
    const float* W     = (const float*)d_in[3];
    const float* asrc  = (const float*)d_in[4];
    const float* adst  = (const float*)d_in[5];
    const float* bias  = (const float*)d_in[6];
    const float* gamma = (const float*)d_in[7];
    const float* beta  = (const float*)d_in[8];
    float* out = (float*)d_out;

    char* ws = (char*)d_ws;
    unsigned short* h = (unsigned short*)ws;                 // 25 MB bf16
    size_t off = (size_t)NROWS * DIM * sizeof(unsigned short);
    unsigned short* wswz = (unsigned short*)(ws + off);      // 32 KB bf16 swizzled
    off += (size_t)DIM * DIM * sizeof(unsigned short);
    float* ssg = (float*)(ws + off);                         // 1.5 MB
    off += (size_t)NROWS * NH * sizeof(float);
    float* sdg = (float*)(ws + off);                         // 1.5 MB
    off += (size_t)NROWS * NH * sizeof(float);
    int* row_ptr = (int*)(ws + off);
    off += (((NNODE + 1) * sizeof(int)) + 15) & ~(size_t)15;
    int* csr_src = (int*)(ws + off);
    off += (size_t)NE * sizeof(int);
    float* csr_ew = (float*)(ws + off);
    off += (size_t)NE * sizeof(float);

    csr_build_k<<<72, 512, 0, stream>>>(ei, ew, W, row_ptr, csr_src, csr_ew, wswz);
    gemm_mfma_k<<<NROWS / 128, 256, 0, stream>>>(x, wswz, asrc, adst, h, ssg, sdg);
    agg_ln_k<<<NROWS / 256, 256, 0, stream>>>(h, ssg, sdg, row_ptr, csr_src, csr_ew,
                                              bias, gamma, beta, out);
}